// Round 6
// baseline (277.293 us; speedup 1.0000x reference)
//
#include <hip/hip_runtime.h>
#include <hip/hip_bf16.h>

typedef float f32x4 __attribute__((ext_vector_type(4)));
typedef short short8 __attribute__((ext_vector_type(8)));

#define NT    325
#define DKK   32
#define NSL   384                 // B*H*T
#define SLICE (NT*DKK)            // 10400
#define TOTE  (NSL*SLICE)         // per-output-tensor elements
#define NKT   21                  // ceil(325/16)
#define PADV  352                 // 11*32, padded m for PV
#define VGRAN (32 * (PADV/8))     // 1408 16B-granules in Vt
// 1/sqrt(32) * log2(e): scores land in log2-domain, exp -> exp2f
#define SCALE2 0.25506372f

// XOR swizzle on short-index (byte bits 4..6).
__device__ __forceinline__ int swz(int sidx, int row) { return sidx ^ ((row & 7) << 3); }

__device__ __forceinline__ unsigned bfu(float f) {
    __hip_bfloat16 h = __float2bfloat16(f);
    return (unsigned)__builtin_bit_cast(unsigned short, h);
}
__device__ __forceinline__ unsigned pk2(float lo, float hi) {
    return bfu(lo) | (bfu(hi) << 16);
}
// split x,y into bf16 hi pair (returned) and bf16 lo pair (written)
__device__ __forceinline__ unsigned pk2_split(float x, float y, unsigned& lopk) {
    const __hip_bfloat16 hx = __float2bfloat16(x);
    const __hip_bfloat16 hy = __float2bfloat16(y);
    const float rx = x - __bfloat162float(hx);
    const float ry = y - __bfloat162float(hy);
    lopk = bfu(rx) | (bfu(ry) << 16);
    return (unsigned)__builtin_bit_cast(unsigned short, hx)
         | ((unsigned)__builtin_bit_cast(unsigned short, hy) << 16);
}

// One block = one (slice, variant); var = bid/384 so every XCD gets all 4
// variants evenly (var = bid&3 put ALL heavy var-1 blocks on XCDs 1,5 -> 2x makespan).
// 4 waves; wave w handles q-tiles w, w+4, ...
// Scores: S^T tile = mfma(A=K-frag, B=Q-frag) -> lane holds S[q=lane&15][m=kt*16+4g+r]
// Variant 1 (K = FlowSpeed(Qs), |K| up to ~1e5) uses 3-term bf16-split MFMA + true max.
// Variants 0,2,3: |s|<~9 in log2 domain -> softmax WITHOUT max subtraction (shift-invariant).
// PV: A-frag assembled from P via 8 shfl + 4 sel per 32-m step; B = Vt (transposed LDS).
__global__ __launch_bounds__(256, 2)
void attn4_mfma(const float* __restrict__ Qf, const float* __restrict__ Kf,
                const float* __restrict__ Vf, const float* __restrict__ Qs,
                const float* __restrict__ Ks, const float* __restrict__ Vs,
                const float* __restrict__ Kj, const float* __restrict__ Vfp,
                float* __restrict__ out)
{
    __shared__ __align__(16) unsigned short Kb[336 * DKK];   // [m][d] bf16 hi (swizzled)
    __shared__ __align__(16) unsigned short Kl[336 * DKK];   // [m][d] bf16 lo (var==1, swizzled)
    __shared__ __align__(16) unsigned short Vt[DKK * PADV];  // [d][m] bf16 (swizzled), m>=325 zeroed

    const int tid = threadIdx.x;
    const int bid = blockIdx.x;
    const int var = bid / NSL;           // XCD-balanced variant assignment
    const int bt  = bid - var * NSL;
    const size_t base = (size_t)bt * SLICE;

    const float *qp, *kp, *vp;
    if      (var == 0) { qp = Qf; kp = Kf; vp = Vf; }
    else if (var == 1) { qp = Kf; kp = Qs; vp = Vf; }   // K = FlowSpeed(Qs)
    else if (var == 2) { qp = Ks; kp = Qf; vp = Vs; }
    else               { qp = Qs; kp = Ks; vp = Vs; }
    float* op = out + (size_t)var * TOTE + base;

    // ---- stage K -> Kb (bf16 hi) [+ Kl lo for var 1], 8 elems/thread ----
    for (int i8 = tid; i8 < SLICE / 8; i8 += 256) {
        const int idx = i8 * 8;
        const int m   = idx >> 5;
        const int sidx = swz(idx, m);
        const float* s = kp + base + idx;
        float4 a = *(const float4*)s;
        float4 b = *(const float4*)(s + 4);
        if (var == 1) {
            const float kj = Kj[m];
            const float rv = 1.0f / (Vfp[m] + 1e-5f);
            a.x = kj * (a.x - a.x * a.x * rv);
            a.y = kj * (a.y - a.y * a.y * rv);
            a.z = kj * (a.z - a.z * a.z * rv);
            a.w = kj * (a.w - a.w * a.w * rv);
            b.x = kj * (b.x - b.x * b.x * rv);
            b.y = kj * (b.y - b.y * b.y * rv);
            b.z = kj * (b.z - b.z * b.z * rv);
            b.w = kj * (b.w - b.w * b.w * rv);
            uint4 hw, lw;
            hw.x = pk2_split(a.x, a.y, lw.x);
            hw.y = pk2_split(a.z, a.w, lw.y);
            hw.z = pk2_split(b.x, b.y, lw.z);
            hw.w = pk2_split(b.z, b.w, lw.w);
            *(uint4*)&Kb[sidx] = hw;
            *(uint4*)&Kl[sidx] = lw;
        } else {
            uint4 pkv;
            pkv.x = pk2(a.x, a.y); pkv.y = pk2(a.z, a.w);
            pkv.z = pk2(b.x, b.y); pkv.w = pk2(b.z, b.w);
            *(uint4*)&Kb[sidx] = pkv;
        }
    }

    // ---- stage V -> Vt (bf16, transposed, zero-padded, swizzled) ----
    for (int gi = tid; gi < VGRAN; gi += 256) {
        const int dd = gi / 44;
        const int m8 = gi - dd * 44;
        const int mb = m8 * 8;
        float v[8];
        #pragma unroll
        for (int i = 0; i < 8; ++i) {
            const int m = mb + i;
            v[i] = (m < NT) ? vp[base + (size_t)m * DKK + dd] : 0.0f;
        }
        uint4 pkv;
        pkv.x = pk2(v[0], v[1]); pkv.y = pk2(v[2], v[3]);
        pkv.z = pk2(v[4], v[5]); pkv.w = pk2(v[6], v[7]);
        *(uint4*)&Vt[swz(dd * PADV + mb, dd)] = pkv;
    }
    __syncthreads();

    const int lane = tid & 63;
    const int wv   = tid >> 6;               // 0..3
    const int c    = lane & 15;
    const int g    = lane >> 4;
    const int src0 = c | ((lane & 16) << 1);  // c + 32*(g&1)
    const int src1 = src0 + 16;
    const bool ghi = (g >= 2);
    const int kswz = (c & 7) << 3;            // row&7 == c&7 for frag reads
    const f32x4 zero = {0.f, 0.f, 0.f, 0.f};

    for (int qt = wv; qt < NKT; qt += 4) {
        // Q B-frag direct from global (coalesced), scale*log2e folded into cvt
        int qrow = qt * 16 + c;
        if (qrow > NT - 1) qrow = NT - 1;
        const float* qsrc = qp + base + (size_t)qrow * DKK + g * 8;
        const float4 qa = *(const float4*)qsrc;
        const float4 qb = *(const float4*)(qsrc + 4);
        uint4 qwh, qwl;
        qwh.x = pk2_split(qa.x * SCALE2, qa.y * SCALE2, qwl.x);
        qwh.y = pk2_split(qa.z * SCALE2, qa.w * SCALE2, qwl.y);
        qwh.z = pk2_split(qb.x * SCALE2, qb.y * SCALE2, qwl.z);
        qwh.w = pk2_split(qb.z * SCALE2, qb.w * SCALE2, qwl.w);
        const short8 qh = __builtin_bit_cast(short8, qwh);
        const short8 ql = __builtin_bit_cast(short8, qwl);

        // ---- scores: 21 independent k-tiles ----
        f32x4 acc[NKT];
        __builtin_amdgcn_s_setprio(1);
        if (var != 1) {
            #pragma unroll
            for (int kt = 0; kt < NKT; ++kt) {
                const short8 kfrag = *(const short8*)&Kb[((kt * 16 + c) * DKK + g * 8) ^ kswz];
                acc[kt] = __builtin_amdgcn_mfma_f32_16x16x32_bf16(kfrag, qh, zero, 0, 0, 0);
            }
        } else {
            #pragma unroll
            for (int kt = 0; kt < NKT; ++kt) {
                const int fi = ((kt * 16 + c) * DKK + g * 8) ^ kswz;
                const short8 kh = *(const short8*)&Kb[fi];
                const short8 kl = *(const short8*)&Kl[fi];
                f32x4 t = __builtin_amdgcn_mfma_f32_16x16x32_bf16(kh, ql, zero, 0, 0, 0);
                t = __builtin_amdgcn_mfma_f32_16x16x32_bf16(kl, qh, t, 0, 0, 0);
                acc[kt] = __builtin_amdgcn_mfma_f32_16x16x32_bf16(kh, qh, t, 0, 0, 0);
            }
        }
        __builtin_amdgcn_s_setprio(0);

        // mask m >= 325 (tile 20: m = 320 + 4g + r)
        #pragma unroll
        for (int r = 0; r < 4; ++r)
            acc[20][r] = (4 * g + r > 4) ? -1e30f : acc[20][r];

        // ---- softmax over m (log2 domain; q = c, copies at lanes ^16, ^32) ----
        // var!=1: |s| <= ~9 -> skip max subtraction entirely (shift-invariant).
        // var==1: huge dynamic range -> true max.
        float ts[4] = {0.f, 0.f, 0.f, 0.f};
        if (var != 1) {
            #pragma unroll
            for (int kt = 0; kt < NKT; ++kt)
                #pragma unroll
                for (int r = 0; r < 4; ++r) {
                    const float e = exp2f(acc[kt][r]);
                    acc[kt][r] = e;
                    ts[r] += e;                     // 4 parallel 21-deep chains
                }
        } else {
            float mv = -1e30f;
            #pragma unroll
            for (int kt = 0; kt < NKT; ++kt)
                #pragma unroll
                for (int r = 0; r < 4; ++r) mv = fmaxf(mv, acc[kt][r]);
            mv = fmaxf(mv, __shfl_xor(mv, 16));
            mv = fmaxf(mv, __shfl_xor(mv, 32));
            #pragma unroll
            for (int kt = 0; kt < NKT; ++kt)
                #pragma unroll
                for (int r = 0; r < 4; ++r) {
                    const float e = exp2f(acc[kt][r] - mv);
                    acc[kt][r] = e;
                    ts[r] += e;
                }
        }
        float sum = (ts[0] + ts[1]) + (ts[2] + ts[3]);
        sum += __shfl_xor(sum, 16);
        sum += __shfl_xor(sum, 32);
        const float inv = 1.0f / sum;

        // ---- pack P to bf16 pairs: P2[kt][p] = P[q=c][m=16kt+4g+2p..+1] ----
        unsigned P2[NKT][2];
        #pragma unroll
        for (int kt = 0; kt < NKT; ++kt) {
            P2[kt][0] = pk2(acc[kt][0], acc[kt][1]);
            P2[kt][1] = pk2(acc[kt][2], acc[kt][3]);
        }

        // ---- PV: O[q][d] = P * V, 11 m-steps of 32 ----
        f32x4 o0 = zero, o1 = zero;
        #pragma unroll
        for (int ks = 0; ks < 10; ++ks) {
            const unsigned x0 = __shfl(P2[2 * ks][0], src0);
            const unsigned x1 = __shfl(P2[2 * ks][1], src0);
            const unsigned x2 = __shfl(P2[2 * ks][0], src1);
            const unsigned x3 = __shfl(P2[2 * ks][1], src1);
            const unsigned y0 = __shfl(P2[2 * ks + 1][0], src0);
            const unsigned y1 = __shfl(P2[2 * ks + 1][1], src0);
            const unsigned y2 = __shfl(P2[2 * ks + 1][0], src1);
            const unsigned y3 = __shfl(P2[2 * ks + 1][1], src1);
            uint4 w;
            w.x = ghi ? y0 : x0; w.y = ghi ? y1 : x1;
            w.z = ghi ? y2 : x2; w.w = ghi ? y3 : x3;
            const short8 afrag = __builtin_bit_cast(short8, w);
            const short8 v0 = *(const short8*)&Vt[( c        * PADV + ks * 32 + g * 8) ^ kswz];
            const short8 v1 = *(const short8*)&Vt[((c + 16)  * PADV + ks * 32 + g * 8) ^ kswz];
            __builtin_amdgcn_s_setprio(1);
            o0 = __builtin_amdgcn_mfma_f32_16x16x32_bf16(afrag, v0, o0, 0, 0, 0);
            o1 = __builtin_amdgcn_mfma_f32_16x16x32_bf16(afrag, v1, o1, 0, 0, 0);
            __builtin_amdgcn_s_setprio(0);
        }
        {   // ks = 10: m = 320..351; g>=2 supplies zeros (kt 21 doesn't exist)
            const unsigned x0 = __shfl(P2[20][0], src0);
            const unsigned x1 = __shfl(P2[20][1], src0);
            const unsigned x2 = __shfl(P2[20][0], src1);
            const unsigned x3 = __shfl(P2[20][1], src1);
            uint4 w;
            w.x = ghi ? 0u : x0; w.y = ghi ? 0u : x1;
            w.z = ghi ? 0u : x2; w.w = ghi ? 0u : x3;
            const short8 afrag = __builtin_bit_cast(short8, w);
            const short8 v0 = *(const short8*)&Vt[( c       * PADV + 320 + g * 8) ^ kswz];
            const short8 v1 = *(const short8*)&Vt[((c + 16) * PADV + 320 + g * 8) ^ kswz];
            o0 = __builtin_amdgcn_mfma_f32_16x16x32_bf16(afrag, v0, o0, 0, 0, 0);
            o1 = __builtin_amdgcn_mfma_f32_16x16x32_bf16(afrag, v1, o1, 0, 0, 0);
        }

        // ---- normalize (inv lives at lane with c == row-in-tile) and store ----
        #pragma unroll
        for (int r = 0; r < 4; ++r) {
            const int row = qt * 16 + 4 * g + r;
            const float iv = __shfl(inv, 4 * g + r);
            if (row < NT) {
                op[(size_t)row * DKK + c]      = o0[r] * iv;
                op[(size_t)row * DKK + c + 16] = o1[r] * iv;
            }
        }
    }
}

extern "C" void kernel_launch(void* const* d_in, const int* in_sizes, int n_in,
                              void* d_out, int out_size, void* d_ws, size_t ws_size,
                              hipStream_t stream) {
    const float* Qf  = (const float*)d_in[0];
    const float* Kf  = (const float*)d_in[1];
    const float* Vf  = (const float*)d_in[2];
    const float* Qs  = (const float*)d_in[3];
    const float* Ks  = (const float*)d_in[4];
    const float* Vs  = (const float*)d_in[5];
    const float* Kj  = (const float*)d_in[6];
    const float* Vfp = (const float*)d_in[7];
    float* out = (float*)d_out;

    attn4_mfma<<<dim3(NSL * 4), dim3(256), 0, stream>>>(Qf, Kf, Vf, Qs, Ks, Vs, Kj, Vfp, out);
}

// Round 7
// 130.015 us; speedup vs baseline: 2.1328x; 2.1328x over previous
//
#include <hip/hip_runtime.h>
#include <hip/hip_bf16.h>

typedef float f32x4 __attribute__((ext_vector_type(4)));
typedef short short8 __attribute__((ext_vector_type(8)));

#define NT    325
#define DKK   32
#define NSL   384                 // B*H*T
#define SLICE (NT*DKK)            // 10400
#define TOTE  (NSL*SLICE)         // per-output-tensor elements
#define NKT   21                  // ceil(325/16)
#define PADV  352                 // 11*32, padded m for PV
#define VGRAN (32 * (PADV/8))     // 1408 16B-granules in Vt
// 1/sqrt(32) * log2(e): scores in log2 domain, exp -> exp2f
#define SCALE2 0.25506372f

// XOR swizzle on short-index (byte bits 4..6).
__device__ __forceinline__ int swz(int sidx, int row) { return sidx ^ ((row & 7) << 3); }

__device__ __forceinline__ unsigned bfu(float f) {
    __hip_bfloat16 h = __float2bfloat16(f);
    return (unsigned)__builtin_bit_cast(unsigned short, h);
}
__device__ __forceinline__ unsigned pk2(float lo, float hi) {
    return bfu(lo) | (bfu(hi) << 16);
}
__device__ __forceinline__ unsigned pk2_split(float x, float y, unsigned& lopk) {
    const __hip_bfloat16 hx = __float2bfloat16(x);
    const __hip_bfloat16 hy = __float2bfloat16(y);
    const float rx = x - __bfloat162float(hx);
    const float ry = y - __bfloat162float(hy);
    lopk = bfu(rx) | (bfu(ry) << 16);
    return (unsigned)__builtin_bit_cast(unsigned short, hx)
         | ((unsigned)__builtin_bit_cast(unsigned short, hy) << 16);
}

// One block = one (slice bt, variant). 8 waves; wave w handles q-tiles w, w+8, ...
// bid mapping: groups of 8 bids hold {2 slices} x {all 4 variants} -> input slices
// shared by 2 variants are read ~simultaneously (L2/LLC reuse, round-6 lesson) AND
// each XCD sees all variants over time (rotation (x+g8)&3).
// FLASH structure: m processed in 11 chunks of 32; PV accumulated per chunk.
// Register state ~80 (vs ~130 full-row) -> 4 waves/SIMD at 512thr/64KB LDS.
// vars 0,2,3: no max subtraction (|s|<~9 in log2 domain, proven round 6).
// var 1 (K = FlowSpeed(Qs), |K| ~1e3+): 3-term bf16-split MFMA + online per-row
// max with wave-uniform defer-skip rescale.
__global__ __launch_bounds__(512, 4)
void attn4_mfma(const float* __restrict__ Qf, const float* __restrict__ Kf,
                const float* __restrict__ Vf, const float* __restrict__ Qs,
                const float* __restrict__ Ks, const float* __restrict__ Vs,
                const float* __restrict__ Kj, const float* __restrict__ Vfp,
                float* __restrict__ out)
{
    __shared__ __align__(16) unsigned short Kb[336 * DKK];   // [m][d] bf16 hi (swizzled)
    __shared__ __align__(16) unsigned short Kl[336 * DKK];   // [m][d] bf16 lo (var==1)
    __shared__ __align__(16) unsigned short Vt[DKK * PADV];  // [d][m] bf16 (swizzled), m>=325 zeroed

    const int tid = threadIdx.x;
    const int bid = blockIdx.x;
    const int g8  = bid >> 3, xx = bid & 7;
    const int var = (xx + g8) & 3;            // rotates across XCDs, local within group
    const int bt  = 2 * g8 + (xx >> 2);
    const size_t base = (size_t)bt * SLICE;

    const float *qp, *kp, *vp;
    if      (var == 0) { qp = Qf; kp = Kf; vp = Vf; }
    else if (var == 1) { qp = Kf; kp = Qs; vp = Vf; }   // K = FlowSpeed(Qs)
    else if (var == 2) { qp = Ks; kp = Qf; vp = Vs; }
    else               { qp = Qs; kp = Ks; vp = Vs; }
    float* op = out + (size_t)var * TOTE + base;

    // ---- stage K -> Kb (bf16 hi) [+ Kl lo for var 1] ----
    for (int i8 = tid; i8 < SLICE / 8; i8 += 512) {
        const int idx = i8 * 8;
        const int m   = idx >> 5;
        const int sidx = swz(idx, m);
        const float* s = kp + base + idx;
        float4 a = *(const float4*)s;
        float4 b = *(const float4*)(s + 4);
        if (var == 1) {
            const float kj = Kj[m];
            const float rv = 1.0f / (Vfp[m] + 1e-5f);
            a.x = kj * (a.x - a.x * a.x * rv);
            a.y = kj * (a.y - a.y * a.y * rv);
            a.z = kj * (a.z - a.z * a.z * rv);
            a.w = kj * (a.w - a.w * a.w * rv);
            b.x = kj * (b.x - b.x * b.x * rv);
            b.y = kj * (b.y - b.y * b.y * rv);
            b.z = kj * (b.z - b.z * b.z * rv);
            b.w = kj * (b.w - b.w * b.w * rv);
            uint4 hw, lw;
            hw.x = pk2_split(a.x, a.y, lw.x);
            hw.y = pk2_split(a.z, a.w, lw.y);
            hw.z = pk2_split(b.x, b.y, lw.z);
            hw.w = pk2_split(b.z, b.w, lw.w);
            *(uint4*)&Kb[sidx] = hw;
            *(uint4*)&Kl[sidx] = lw;
        } else {
            uint4 pkv;
            pkv.x = pk2(a.x, a.y); pkv.y = pk2(a.z, a.w);
            pkv.z = pk2(b.x, b.y); pkv.w = pk2(b.z, b.w);
            *(uint4*)&Kb[sidx] = pkv;
        }
    }

    // ---- stage V -> Vt (bf16, transposed, zero-padded, swizzled) ----
    for (int gi = tid; gi < VGRAN; gi += 512) {
        const int dd = gi / 44;
        const int m8 = gi - dd * 44;
        const int mb = m8 * 8;
        float v[8];
        #pragma unroll
        for (int i = 0; i < 8; ++i) {
            const int m = mb + i;
            v[i] = (m < NT) ? vp[base + (size_t)m * DKK + dd] : 0.0f;
        }
        uint4 pkv;
        pkv.x = pk2(v[0], v[1]); pkv.y = pk2(v[2], v[3]);
        pkv.z = pk2(v[4], v[5]); pkv.w = pk2(v[6], v[7]);
        *(uint4*)&Vt[swz(dd * PADV + mb, dd)] = pkv;
    }
    __syncthreads();

    const int lane = tid & 63;
    const int wv   = tid >> 6;                // 0..7
    const int c    = lane & 15;
    const int g    = lane >> 4;
    const int src0 = c | ((lane & 16) << 1);  // c + 32*(g&1)
    const int src1 = src0 + 16;
    const bool ghi = (g >= 2);
    const int kswz = (c & 7) << 3;
    const f32x4 zero = {0.f, 0.f, 0.f, 0.f};

    int qt = wv;
    float4 qa, qb;
    {   // preload first Q frag
        int qr = qt * 16 + c; if (qr > NT - 1) qr = NT - 1;
        const float* s = qp + base + (size_t)qr * DKK + g * 8;
        qa = *(const float4*)s; qb = *(const float4*)(s + 4);
    }

    for (; qt < NKT; qt += 8) {
        float4 na, nb;
        const bool more = (qt + 8) < NKT;
        if (more) {   // prefetch next Q frag; latency hides under chunk loop
            int qr = (qt + 8) * 16 + c; if (qr > NT - 1) qr = NT - 1;
            const float* s = qp + base + (size_t)qr * DKK + g * 8;
            na = *(const float4*)s; nb = *(const float4*)(s + 4);
        }

        uint4 qwh, qwl;
        qwh.x = pk2_split(qa.x * SCALE2, qa.y * SCALE2, qwl.x);
        qwh.y = pk2_split(qa.z * SCALE2, qa.w * SCALE2, qwl.y);
        qwh.z = pk2_split(qb.x * SCALE2, qb.y * SCALE2, qwl.z);
        qwh.w = pk2_split(qb.z * SCALE2, qb.w * SCALE2, qwl.w);
        const short8 qh = __builtin_bit_cast(short8, qwh);
        const short8 ql = __builtin_bit_cast(short8, qwl);

        f32x4 o0 = zero, o1 = zero;
        float ts = 0.f;
        float mrow = -1e30f;

        #pragma unroll
        for (int ks = 0; ks < 11; ++ks) {
            const int fi0 = (((2 * ks) * 16 + c) * DKK + g * 8) ^ kswz;
            const int fi1 = fi0 + 16 * DKK;     // +512: doesn't touch swizzle bits
            f32x4 a0, a1;

            __builtin_amdgcn_s_setprio(1);
            if (var != 1) {
                const short8 k0 = *(const short8*)&Kb[fi0];
                a0 = __builtin_amdgcn_mfma_f32_16x16x32_bf16(k0, qh, zero, 0, 0, 0);
                if (ks < 10) {
                    const short8 k1 = *(const short8*)&Kb[fi1];
                    a1 = __builtin_amdgcn_mfma_f32_16x16x32_bf16(k1, qh, zero, 0, 0, 0);
                }
            } else {
                {
                    const short8 kh = *(const short8*)&Kb[fi0];
                    const short8 kl = *(const short8*)&Kl[fi0];
                    f32x4 t = __builtin_amdgcn_mfma_f32_16x16x32_bf16(kh, ql, zero, 0, 0, 0);
                    t = __builtin_amdgcn_mfma_f32_16x16x32_bf16(kl, qh, t, 0, 0, 0);
                    a0 = __builtin_amdgcn_mfma_f32_16x16x32_bf16(kh, qh, t, 0, 0, 0);
                }
                if (ks < 10) {
                    const short8 kh = *(const short8*)&Kb[fi1];
                    const short8 kl = *(const short8*)&Kl[fi1];
                    f32x4 t = __builtin_amdgcn_mfma_f32_16x16x32_bf16(kh, ql, zero, 0, 0, 0);
                    t = __builtin_amdgcn_mfma_f32_16x16x32_bf16(kl, qh, t, 0, 0, 0);
                    a1 = __builtin_amdgcn_mfma_f32_16x16x32_bf16(kh, qh, t, 0, 0, 0);
                }
            }
            __builtin_amdgcn_s_setprio(0);

            if (ks == 10) {   // mask m >= 325 (tile 20: m = 320 + 4g + r)
                #pragma unroll
                for (int r = 0; r < 4; ++r)
                    a0[r] = (4 * g + r > 4) ? -1e30f : a0[r];
            }

            if (var == 1) {
                float pm = fmaxf(fmaxf(a0[0], a0[1]), fmaxf(a0[2], a0[3]));
                if (ks < 10)
                    pm = fmaxf(pm, fmaxf(fmaxf(a1[0], a1[1]), fmaxf(a1[2], a1[3])));
                pm = fmaxf(pm, __shfl_xor(pm, 16));
                pm = fmaxf(pm, __shfl_xor(pm, 32));
                if (__any(pm > mrow)) {          // wave-uniform defer-skip
                    const float mnew = fmaxf(mrow, pm);
                    const float f = exp2f(mrow - mnew);   // 0 on first chunk
                    mrow = mnew;
                    ts *= f;
                    #pragma unroll
                    for (int r = 0; r < 4; ++r) {
                        const float fr = __shfl(f, 4 * g + r);  // f of output row
                        o0[r] *= fr; o1[r] *= fr;
                    }
                }
                #pragma unroll
                for (int r = 0; r < 4; ++r) { a0[r] = exp2f(a0[r] - mrow); ts += a0[r]; }
                if (ks < 10) {
                    #pragma unroll
                    for (int r = 0; r < 4; ++r) { a1[r] = exp2f(a1[r] - mrow); ts += a1[r]; }
                }
            } else {
                #pragma unroll
                for (int r = 0; r < 4; ++r) { a0[r] = exp2f(a0[r]); ts += a0[r]; }
                if (ks < 10) {
                    #pragma unroll
                    for (int r = 0; r < 4; ++r) { a1[r] = exp2f(a1[r]); ts += a1[r]; }
                }
            }

            // pack P -> bf16, assemble PV A-frag (8 bpermute + 4 sel)
            const unsigned pA0 = pk2(a0[0], a0[1]), pA1 = pk2(a0[2], a0[3]);
            const unsigned x0 = __shfl(pA0, src0), x1 = __shfl(pA1, src0);
            const unsigned x2 = __shfl(pA0, src1), x3 = __shfl(pA1, src1);
            uint4 w;
            if (ks < 10) {
                const unsigned pB0 = pk2(a1[0], a1[1]), pB1 = pk2(a1[2], a1[3]);
                const unsigned y0 = __shfl(pB0, src0), y1 = __shfl(pB1, src0);
                const unsigned y2 = __shfl(pB0, src1), y3 = __shfl(pB1, src1);
                w.x = ghi ? y0 : x0; w.y = ghi ? y1 : x1;
                w.z = ghi ? y2 : x2; w.w = ghi ? y3 : x3;
            } else {
                w.x = ghi ? 0u : x0; w.y = ghi ? 0u : x1;
                w.z = ghi ? 0u : x2; w.w = ghi ? 0u : x3;
            }
            const short8 af = __builtin_bit_cast(short8, w);
            const short8 v0 = *(const short8*)&Vt[( c        * PADV + ks * 32 + g * 8) ^ kswz];
            const short8 v1 = *(const short8*)&Vt[((c + 16)  * PADV + ks * 32 + g * 8) ^ kswz];
            __builtin_amdgcn_s_setprio(1);
            o0 = __builtin_amdgcn_mfma_f32_16x16x32_bf16(af, v0, o0, 0, 0, 0);
            o1 = __builtin_amdgcn_mfma_f32_16x16x32_bf16(af, v1, o1, 0, 0, 0);
            __builtin_amdgcn_s_setprio(0);
        }

        ts += __shfl_xor(ts, 16);
        ts += __shfl_xor(ts, 32);
        const float inv = 1.0f / ts;

        #pragma unroll
        for (int r = 0; r < 4; ++r) {
            const int row = qt * 16 + 4 * g + r;
            const float iv = __shfl(inv, 4 * g + r);
            if (row < NT) {
                op[(size_t)row * DKK + c]      = o0[r] * iv;
                op[(size_t)row * DKK + c + 16] = o1[r] * iv;
            }
        }
        qa = na; qb = nb;
    }
}

extern "C" void kernel_launch(void* const* d_in, const int* in_sizes, int n_in,
                              void* d_out, int out_size, void* d_ws, size_t ws_size,
                              hipStream_t stream) {
    const float* Qf  = (const float*)d_in[0];
    const float* Kf  = (const float*)d_in[1];
    const float* Vf  = (const float*)d_in[2];
    const float* Qs  = (const float*)d_in[3];
    const float* Ks  = (const float*)d_in[4];
    const float* Vs  = (const float*)d_in[5];
    const float* Kj  = (const float*)d_in[6];
    const float* Vfp = (const float*)d_in[7];
    float* out = (float*)d_out;

    attn4_mfma<<<dim3(NSL * 4), dim3(512), 0, stream>>>(Qf, Kf, Vf, Qs, Ks, Vs, Kj, Vfp, out);
}

// Round 8
// 121.065 us; speedup vs baseline: 2.2904x; 1.0739x over previous
//
#include <hip/hip_runtime.h>
#include <hip/hip_bf16.h>

typedef float f32x4 __attribute__((ext_vector_type(4)));
typedef short short8 __attribute__((ext_vector_type(8)));

#define NT    325
#define DKK   32
#define NSL   384                 // B*H*T
#define SLICE (NT*DKK)            // 10400
#define TOTE  (NSL*SLICE)         // per-output-tensor elements
#define NKT   21                  // ceil(325/16)
#define PADV  352                 // 11*32, padded m for PV
#define VGRAN (32 * (PADV/8))     // 1408 16B-granules in Vt
#define PP    40                  // P_lds pitch in shorts (16B-aligned rows, ~2-way banks)
// 1/sqrt(32) * log2(e): scores in log2 domain, exp -> exp2f
#define SCALE2 0.25506372f

// XOR swizzle on short-index (byte bits 4..6).
__device__ __forceinline__ int swz(int sidx, int row) { return sidx ^ ((row & 7) << 3); }

// HW packed f32->bf16 pair convert (1 instr vs ~18 for the software-RNE pair).
__device__ __forceinline__ unsigned cvtpk(float lo, float hi) {
    unsigned r;
    asm("v_cvt_pk_bf16_f32 %0, %1, %2" : "=v"(r) : "v"(lo), "v"(hi));
    return r;
}
// split (x,y) -> bf16-hi packed word (returned) + bf16-lo packed word (Markidis)
__device__ __forceinline__ unsigned pk2_split(float x, float y, unsigned& lopk) {
    const unsigned hi = cvtpk(x, y);
    const float hx = __builtin_bit_cast(float, hi << 16);
    const float hy = __builtin_bit_cast(float, hi & 0xffff0000u);
    lopk = cvtpk(x - hx, y - hy);
    return hi;
}

// One block = one (slice bt, variant). 8 waves; wave w handles q-tiles w, w+8, ...
// bid mapping (round-7, proven): groups of 8 bids = {2 slices} x {4 variants} ->
// L2 reuse between the 2 variants reading each tensor + variant rotation across XCDs.
// FLASH: m in 11 chunks of 32, PV accumulated per chunk.
// vars 0,2,3: no max subtraction (|s|<~9 in log2 domain). var 1: 3-term bf16-split
// MFMA + online max with wave-uniform defer-skip.
// P repack: per-wave LDS round-trip (2 ds_write_b64 + 1 ds_read_b128), replacing
// 12 ds_bpermute + 4 cndmask per chunk (round-7 bottleneck).
__global__ __launch_bounds__(512, 4)
void attn4_mfma(const float* __restrict__ Qf, const float* __restrict__ Kf,
                const float* __restrict__ Vf, const float* __restrict__ Qs,
                const float* __restrict__ Ks, const float* __restrict__ Vs,
                const float* __restrict__ Kj, const float* __restrict__ Vfp,
                float* __restrict__ out)
{
    __shared__ __align__(16) unsigned short Kb[336 * DKK];   // [m][d] bf16 hi (swizzled)
    __shared__ __align__(16) unsigned short Kl[336 * DKK];   // [m][d] bf16 lo (var==1)
    __shared__ __align__(16) unsigned short Vt[DKK * PADV];  // [d][m] bf16 (swizzled)
    __shared__ __align__(16) unsigned short Pl[8][16 * PP];  // per-wave P tile [q][m-chunk]

    const int tid = threadIdx.x;
    const int bid = blockIdx.x;
    const int g8  = bid >> 3, xx = bid & 7;
    const int var = (xx + g8) & 3;
    const int bt  = 2 * g8 + (xx >> 2);
    const size_t base = (size_t)bt * SLICE;

    const float *qp, *kp, *vp;
    if      (var == 0) { qp = Qf; kp = Kf; vp = Vf; }
    else if (var == 1) { qp = Kf; kp = Qs; vp = Vf; }   // K = FlowSpeed(Qs)
    else if (var == 2) { qp = Ks; kp = Qf; vp = Vs; }
    else               { qp = Qs; kp = Ks; vp = Vs; }
    float* op = out + (size_t)var * TOTE + base;

    // ---- stage K -> Kb (bf16 hi) [+ Kl lo for var 1] ----
    for (int i8 = tid; i8 < SLICE / 8; i8 += 512) {
        const int idx = i8 * 8;
        const int m   = idx >> 5;
        const int sidx = swz(idx, m);
        const float* s = kp + base + idx;
        float4 a = *(const float4*)s;
        float4 b = *(const float4*)(s + 4);
        if (var == 1) {
            const float kj = Kj[m];
            const float rv = 1.0f / (Vfp[m] + 1e-5f);
            a.x = kj * (a.x - a.x * a.x * rv);
            a.y = kj * (a.y - a.y * a.y * rv);
            a.z = kj * (a.z - a.z * a.z * rv);
            a.w = kj * (a.w - a.w * a.w * rv);
            b.x = kj * (b.x - b.x * b.x * rv);
            b.y = kj * (b.y - b.y * b.y * rv);
            b.z = kj * (b.z - b.z * b.z * rv);
            b.w = kj * (b.w - b.w * b.w * rv);
            uint4 hw, lw;
            hw.x = pk2_split(a.x, a.y, lw.x);
            hw.y = pk2_split(a.z, a.w, lw.y);
            hw.z = pk2_split(b.x, b.y, lw.z);
            hw.w = pk2_split(b.z, b.w, lw.w);
            *(uint4*)&Kb[sidx] = hw;
            *(uint4*)&Kl[sidx] = lw;
        } else {
            uint4 pkv;
            pkv.x = cvtpk(a.x, a.y); pkv.y = cvtpk(a.z, a.w);
            pkv.z = cvtpk(b.x, b.y); pkv.w = cvtpk(b.z, b.w);
            *(uint4*)&Kb[sidx] = pkv;
        }
    }

    // ---- stage V -> Vt (bf16, transposed, zero-padded, swizzled) ----
    for (int gi = tid; gi < VGRAN; gi += 512) {
        const int dd = gi / 44;
        const int m8 = gi - dd * 44;
        const int mb = m8 * 8;
        float v[8];
        #pragma unroll
        for (int i = 0; i < 8; ++i) {
            const int m = mb + i;
            v[i] = (m < NT) ? vp[base + (size_t)m * DKK + dd] : 0.0f;
        }
        uint4 pkv;
        pkv.x = cvtpk(v[0], v[1]); pkv.y = cvtpk(v[2], v[3]);
        pkv.z = cvtpk(v[4], v[5]); pkv.w = cvtpk(v[6], v[7]);
        *(uint4*)&Vt[swz(dd * PADV + mb, dd)] = pkv;
    }
    __syncthreads();

    const int lane = tid & 63;
    const int wv   = tid >> 6;                // 0..7
    const int c    = lane & 15;
    const int g    = lane >> 4;
    const int kswz = (c & 7) << 3;
    const f32x4 zero = {0.f, 0.f, 0.f, 0.f};
    unsigned short* const pw = &Pl[wv][0];

    int qt = wv;
    float4 qa, qb;
    {   // preload first Q frag
        int qr = qt * 16 + c; if (qr > NT - 1) qr = NT - 1;
        const float* s = qp + base + (size_t)qr * DKK + g * 8;
        qa = *(const float4*)s; qb = *(const float4*)(s + 4);
    }

    for (; qt < NKT; qt += 8) {
        float4 na, nb;
        const bool more = (qt + 8) < NKT;
        if (more) {
            int qr = (qt + 8) * 16 + c; if (qr > NT - 1) qr = NT - 1;
            const float* s = qp + base + (size_t)qr * DKK + g * 8;
            na = *(const float4*)s; nb = *(const float4*)(s + 4);
        }

        uint4 qwh, qwl;
        qwh.x = pk2_split(qa.x * SCALE2, qa.y * SCALE2, qwl.x);
        qwh.y = pk2_split(qa.z * SCALE2, qa.w * SCALE2, qwl.y);
        qwh.z = pk2_split(qb.x * SCALE2, qb.y * SCALE2, qwl.z);
        qwh.w = pk2_split(qb.z * SCALE2, qb.w * SCALE2, qwl.w);
        const short8 qh = __builtin_bit_cast(short8, qwh);
        const short8 ql = __builtin_bit_cast(short8, qwl);

        f32x4 o0 = zero, o1 = zero;
        float ts = 0.f;
        float mrow = -1e30f;

        #pragma unroll
        for (int ks = 0; ks < 11; ++ks) {
            const int fi0 = (((2 * ks) * 16 + c) * DKK + g * 8) ^ kswz;
            const int fi1 = fi0 + 16 * DKK;     // +512: doesn't touch swizzle bits
            f32x4 a0, a1;

            __builtin_amdgcn_s_setprio(1);
            if (var != 1) {
                const short8 k0 = *(const short8*)&Kb[fi0];
                a0 = __builtin_amdgcn_mfma_f32_16x16x32_bf16(k0, qh, zero, 0, 0, 0);
                if (ks < 10) {
                    const short8 k1 = *(const short8*)&Kb[fi1];
                    a1 = __builtin_amdgcn_mfma_f32_16x16x32_bf16(k1, qh, zero, 0, 0, 0);
                }
            } else {
                {
                    const short8 kh = *(const short8*)&Kb[fi0];
                    const short8 kl = *(const short8*)&Kl[fi0];
                    f32x4 t = __builtin_amdgcn_mfma_f32_16x16x32_bf16(kh, ql, zero, 0, 0, 0);
                    t = __builtin_amdgcn_mfma_f32_16x16x32_bf16(kl, qh, t, 0, 0, 0);
                    a0 = __builtin_amdgcn_mfma_f32_16x16x32_bf16(kh, qh, t, 0, 0, 0);
                }
                if (ks < 10) {
                    const short8 kh = *(const short8*)&Kb[fi1];
                    const short8 kl = *(const short8*)&Kl[fi1];
                    f32x4 t = __builtin_amdgcn_mfma_f32_16x16x32_bf16(kh, ql, zero, 0, 0, 0);
                    t = __builtin_amdgcn_mfma_f32_16x16x32_bf16(kl, qh, t, 0, 0, 0);
                    a1 = __builtin_amdgcn_mfma_f32_16x16x32_bf16(kh, qh, t, 0, 0, 0);
                }
            }
            __builtin_amdgcn_s_setprio(0);

            if (ks == 10) {   // mask m >= 325 (tile 20: m = 320 + 4g + r)
                #pragma unroll
                for (int r = 0; r < 4; ++r)
                    a0[r] = (4 * g + r > 4) ? -1e30f : a0[r];
            }

            if (var == 1) {
                float pm = fmaxf(fmaxf(a0[0], a0[1]), fmaxf(a0[2], a0[3]));
                if (ks < 10)
                    pm = fmaxf(pm, fmaxf(fmaxf(a1[0], a1[1]), fmaxf(a1[2], a1[3])));
                pm = fmaxf(pm, __shfl_xor(pm, 16));
                pm = fmaxf(pm, __shfl_xor(pm, 32));
                if (__any(pm > mrow)) {          // wave-uniform defer-skip
                    const float mnew = fmaxf(mrow, pm);
                    const float f = exp2f(mrow - mnew);   // 0 on first chunk
                    mrow = mnew;
                    ts *= f;
                    #pragma unroll
                    for (int r = 0; r < 4; ++r) {
                        const float fr = __shfl(f, 4 * g + r);
                        o0[r] *= fr; o1[r] *= fr;
                    }
                }
                #pragma unroll
                for (int r = 0; r < 4; ++r) { a0[r] = exp2f(a0[r] - mrow); ts += a0[r]; }
                if (ks < 10) {
                    #pragma unroll
                    for (int r = 0; r < 4; ++r) { a1[r] = exp2f(a1[r] - mrow); ts += a1[r]; }
                }
            } else {
                #pragma unroll
                for (int r = 0; r < 4; ++r) { a0[r] = exp2f(a0[r]); ts += a0[r]; }
                if (ks < 10) {
                    #pragma unroll
                    for (int r = 0; r < 4; ++r) { a1[r] = exp2f(a1[r]); ts += a1[r]; }
                }
            }

            // ---- P repack via per-wave LDS (in-order within wave, no barrier) ----
            // write S[q=c][m=4g..4g+3] (tile A) and [m=16+4g..] (tile B) as b64s
            {
                uint2 wa; wa.x = cvtpk(a0[0], a0[1]); wa.y = cvtpk(a0[2], a0[3]);
                *(uint2*)&pw[c * PP + 4 * g] = wa;
                uint2 wb;
                if (ks < 10) { wb.x = cvtpk(a1[0], a1[1]); wb.y = cvtpk(a1[2], a1[3]); }
                else         { wb.x = 0u; wb.y = 0u; }
                *(uint2*)&pw[c * PP + 16 + 4 * g] = wb;
            }
            // read A-frag: P[q=c][k=8g..8g+7] (16B-aligned, ~2-way banks = free)
            const short8 af = *(const short8*)&pw[c * PP + 8 * g];
            const short8 v0 = *(const short8*)&Vt[( c        * PADV + ks * 32 + g * 8) ^ kswz];
            const short8 v1 = *(const short8*)&Vt[((c + 16)  * PADV + ks * 32 + g * 8) ^ kswz];
            __builtin_amdgcn_s_setprio(1);
            o0 = __builtin_amdgcn_mfma_f32_16x16x32_bf16(af, v0, o0, 0, 0, 0);
            o1 = __builtin_amdgcn_mfma_f32_16x16x32_bf16(af, v1, o1, 0, 0, 0);
            __builtin_amdgcn_s_setprio(0);
        }

        ts += __shfl_xor(ts, 16);
        ts += __shfl_xor(ts, 32);
        const float inv = 1.0f / ts;

        #pragma unroll
        for (int r = 0; r < 4; ++r) {
            const int row = qt * 16 + 4 * g + r;
            const float iv = __shfl(inv, 4 * g + r);
            if (row < NT) {
                op[(size_t)row * DKK + c]      = o0[r] * iv;
                op[(size_t)row * DKK + c + 16] = o1[r] * iv;
            }
        }
        qa = na; qb = nb;
    }
}

extern "C" void kernel_launch(void* const* d_in, const int* in_sizes, int n_in,
                              void* d_out, int out_size, void* d_ws, size_t ws_size,
                              hipStream_t stream) {
    const float* Qf  = (const float*)d_in[0];
    const float* Kf  = (const float*)d_in[1];
    const float* Vf  = (const float*)d_in[2];
    const float* Qs  = (const float*)d_in[3];
    const float* Ks  = (const float*)d_in[4];
    const float* Vs  = (const float*)d_in[5];
    const float* Kj  = (const float*)d_in[6];
    const float* Vfp = (const float*)d_in[7];
    float* out = (float*)d_out;

    attn4_mfma<<<dim3(NSL * 4), dim3(512), 0, stream>>>(Qf, Kf, Vf, Qs, Ks, Vs, Kj, Vfp, out);
}